// Round 14
// baseline (542.285 us; speedup 1.0000x reference)
//
#include <hip/hip_runtime.h>
#include <hip/hip_bf16.h>
#include <stdint.h>

typedef __bf16 bf16x8 __attribute__((ext_vector_type(8)));
typedef __bf16 bf16x2 __attribute__((ext_vector_type(2)));
typedef float  f32x4  __attribute__((ext_vector_type(4)));

template <int V> struct ic { static constexpr int value = V; };

__device__ __forceinline__ void gload_lds16(const void* g, void* l) {
  __builtin_amdgcn_global_load_lds(
      (const __attribute__((address_space(1))) void*)g,
      (__attribute__((address_space(3))) void*)l, 16, 0, 0);
}

// ---------------- RMSNorm: fp32 row (H=2048) -> bf16 row ----------------
__global__ __launch_bounds__(256) void rmsnorm_kernel(
    const float* __restrict__ x, const float* __restrict__ w,
    __bf16* __restrict__ out) {
  constexpr int H = 2048;
  const int row = blockIdx.x;
  const int t = threadIdx.x;
  const float4* xr = (const float4*)(x + (size_t)row * H);
  float4 a = xr[t * 2 + 0];
  float4 b = xr[t * 2 + 1];
  float ss = a.x*a.x + a.y*a.y + a.z*a.z + a.w*a.w
           + b.x*b.x + b.y*b.y + b.z*b.z + b.w*b.w;
#pragma unroll
  for (int o = 32; o > 0; o >>= 1) ss += __shfl_xor(ss, o);
  __shared__ float red[4];
  if ((t & 63) == 0) red[t >> 6] = ss;
  __syncthreads();
  float tot = red[0] + red[1] + red[2] + red[3];
  float r = rsqrtf(tot * (1.0f / H) + 1e-6f);
  const float4* wr4 = (const float4*)w;
  float4 wa = wr4[t * 2 + 0];
  float4 wb = wr4[t * 2 + 1];
  bf16x8 ov;
  ov[0] = (__bf16)(a.x * wa.x * r);
  ov[1] = (__bf16)(a.y * wa.y * r);
  ov[2] = (__bf16)(a.z * wa.z * r);
  ov[3] = (__bf16)(a.w * wa.w * r);
  ov[4] = (__bf16)(b.x * wb.x * r);
  ov[5] = (__bf16)(b.y * wb.y * r);
  ov[6] = (__bf16)(b.z * wb.z * r);
  ov[7] = (__bf16)(b.w * wb.w * r);
  *(bf16x8*)(out + (size_t)row * H + (size_t)t * 8) = ov;
}

// ---------------- AWQ dequant -> transposed bf16 weight (N x K) ----------------
template <int GU>
__global__ __launch_bounds__(256) void dequant_t_kernel(
    const int* __restrict__ qw, const int* __restrict__ qz,
    const float* __restrict__ sc, __bf16* __restrict__ wt,
    int K, int Cp, int Nfull) {
  const int t = threadIdx.x;
  const int k0 = blockIdx.x * 128 + (t & 63) * 2;
  const int c0 = blockIdx.y * 64 + (t >> 6) * 16;
  const int g = k0 >> 7;
  const uint32_t* qw0 = (const uint32_t*)qw + (size_t)k0 * Cp + c0;
  const uint32_t* qw1 = qw0 + Cp;
  const uint32_t* qzr = (const uint32_t*)qz + (size_t)g * Cp + c0;
  const float* scr = sc + (size_t)g * Nfull + (size_t)c0 * 8;

  uint32_t u0[16], u1[16], z[16];
#pragma unroll
  for (int j = 0; j < 4; j++) {
    *(int4*)(&u0[j*4]) = *(const int4*)(qw0 + j*4);
    *(int4*)(&u1[j*4]) = *(const int4*)(qw1 + j*4);
    *(int4*)(&z[j*4])  = *(const int4*)(qzr + j*4);
  }

#pragma unroll
  for (int i = 0; i < 16; i++) {
#pragma unroll
    for (int s = 0; s < 8; s++) {
      const int sh = ((s >> 1) * 4) + ((s & 1) ? 16 : 0);
      const float zf = (float)((z[i] >> sh) & 15u);
      const float scv = scr[i * 8 + s];
      const float w0 = ((float)((u0[i] >> sh) & 15u) - zf) * scv;
      const float w1 = ((float)((u1[i] >> sh) & 15u) - zf) * scv;
      const int n = (c0 + i) * 8 + s;
      int row;
      if (GU) row = (n < 8192) ? ((n >> 4) * 32 + (n & 15))
                               : (((n - 8192) >> 4) * 32 + 16 + (n & 15));
      else    row = n;
      bf16x2 pv = {(__bf16)w0, (__bf16)w1};
      *(bf16x2*)(wt + (size_t)row * K + k0) = pv;
    }
  }
}

// ------- 256x256 gu GEMM: quadrant-phased interior (unchanged from r13) ------
// Phases = C-quadrants. Reads: ph0 (A mi0-3 + B ni0-1), ph1 (B ni2-3),
// ph2 (A mi4-7), ph3 none. Stages: ph0 A-odd(t+1); ph2 B01(t+2);
// ph3 post-publish B23(t+2)+A-even(t+2). Steady vmcnt(2); prologue vmcnt(6).
// Ledger re-traced race-free (every overwrite >=1 barrier after its readers'
// consuming MFMA; no same-phase read/overwrite overlap).
template <int KC>
__global__ __launch_bounds__(512, 2) void gemm256_kernel(
    const __bf16* __restrict__ A, const __bf16* __restrict__ Bt,
    __bf16* __restrict__ act, int M) {
  constexpr int NT = KC / 64;

  __shared__ alignas(16) __bf16 As[8 * 4096];
  __shared__ alignas(16) __bf16 Bs[8 * 4096];

  const int t = threadIdx.x;
  const int w = t >> 6, l = t & 63;
  const int lm = l & 15, kb = l >> 4;
  const int l7 = lm & 7;
  const int wm = w >> 2, wn = w & 3;

  const size_t stat = (size_t)(t >> 3) * KC + (size_t)(((t & 7) ^ ((t >> 3) & 7)) << 3);

  const int nwg = gridDim.x;
  const int bid = blockIdx.x;
  const int swz = (bid & 7) * (nwg >> 3) + (bid >> 3);
  const int nbm = M >> 8;
  const int per_g = nbm * 8;
  const int grp = swz / per_g, v = swz % per_g;
  const int bm0 = (v % nbm) * 256;
  const int bn0 = (grp * 8 + v / nbm) * 256;

  const __bf16* Ab = A + (size_t)bm0 * KC;
  const __bf16* Bb = Bt + (size_t)bn0 * KC;

  const uint32_t gsw0 = (uint32_t)((kb ^ l7) << 4);
  const uint32_t gsw1 = (uint32_t)(((4 + kb) ^ l7) << 4);
  const uint32_t arow = (uint32_t)(wm * 16384 + lm * 128);
  const uint32_t aoff0 = arow + gsw0, aoff1 = arow + gsw1;
  const uint32_t brow = (uint32_t)(wn * 8192 + lm * 128);
  const uint32_t boff0 = brow + gsw0, boff1 = brow + gsw1;
  const char* AsC = (const char*)As;
  const char* BsC = (const char*)Bs;

  f32x4 acc[8][4] = {};
  bf16x8 af4[4][2];
  bf16x8 bfr4[4][2];

  auto ldAhalf = [&](int dD, int half) {
#pragma unroll
    for (int m2 = 0; m2 < 4; ++m2) {
      const int mi = half * 4 + m2;
      const uint32_t imA = (uint32_t)((dD * 4 + (mi >> 2)) * 8192 + (mi & 3) * 2048);
      af4[m2][0] = *(const bf16x8*)(AsC + aoff0 + imA);
      af4[m2][1] = *(const bf16x8*)(AsC + aoff1 + imA);
    }
  };
  auto ldBpair = [&](int dD, int p) {
#pragma unroll
    for (int j = 0; j < 2; ++j) {
      const int ni = p * 2 + j;
      const uint32_t imB = (uint32_t)(dD * 32768 + ni * 2048);
      bfr4[ni][0] = *(const bf16x8*)(BsC + boff0 + imB);
      bfr4[ni][1] = *(const bf16x8*)(BsC + boff1 + imB);
    }
  };
  auto mfmaQ = [&](int qm, int qn) {
    __builtin_amdgcn_s_setprio(1);
#pragma unroll
    for (int kk = 0; kk < 2; ++kk)
#pragma unroll
      for (int j = 0; j < 2; ++j)
#pragma unroll
        for (int m2 = 0; m2 < 4; ++m2)
          acc[qm * 4 + m2][qn * 2 + j] = __builtin_amdgcn_mfma_f32_16x16x32_bf16(
              af4[m2][kk], bfr4[qn * 2 + j][kk], acc[qm * 4 + m2][qn * 2 + j], 0, 0, 0);
    __builtin_amdgcn_s_setprio(0);
  };

  // ---- prologue: A(0)x4, B(0)x4, B(1)x4, A(1)-even x2; vmcnt(6) ----
#pragma unroll
  for (int qa = 0; qa < 4; ++qa)
    gload_lds16(Ab + stat + (size_t)(qa * 64) * KC, As + qa * 4096 + t * 8);
#pragma unroll
  for (int qb = 0; qb < 4; ++qb)
    gload_lds16(Bb + stat + (size_t)(qb * 64) * KC, Bs + qb * 4096 + t * 8);
#pragma unroll
  for (int qb = 0; qb < 4; ++qb)
    gload_lds16(Bb + stat + (size_t)(qb * 64) * KC + 64, Bs + (4 + qb) * 4096 + t * 8);
  gload_lds16(Ab + stat + 64, As + 4 * 4096 + t * 8);
  gload_lds16(Ab + stat + (size_t)128 * KC + 64, As + 6 * 4096 + t * 8);
  asm volatile("s_waitcnt vmcnt(6)" ::: "memory");
  __builtin_amdgcn_s_barrier();

  const __bf16* pA0 = Ab + stat + 128;
  const __bf16* pA1 = Ab + stat + (size_t)64 * KC + 64;
  const __bf16* pA2 = Ab + stat + (size_t)128 * KC + 128;
  const __bf16* pA3 = Ab + stat + (size_t)192 * KC + 64;
  const __bf16* pB0 = Bb + stat + 128;
  const __bf16* pB1 = Bb + stat + (size_t)64 * KC + 128;
  const __bf16* pB2 = Bb + stat + (size_t)128 * KC + 128;
  const __bf16* pB3 = Bb + stat + (size_t)192 * KC + 128;

  auto tile = [&](auto Dc, auto Sc) {
    constexpr int D = decltype(Dc)::value;
    constexpr int STG = decltype(Sc)::value;
    // ---- ph0: reads (A mi0-3, B ni0-1); stage A-odd(t+1) -> other dbuf ----
    ldAhalf(D, 0);
    ldBpair(D, 0);
    asm volatile("" ::: "memory");
    if (STG >= 1) {
      gload_lds16(pA1, As + ((D ^ 1) * 4 + 1) * 4096 + t * 8);
      gload_lds16(pA3, As + ((D ^ 1) * 4 + 3) * 4096 + t * 8);
    }
    __builtin_amdgcn_s_barrier();
    mfmaQ(0, 0);
    __builtin_amdgcn_s_barrier();
    // ---- ph1: reads (B ni2-3) ----
    ldBpair(D, 1);
    asm volatile("" ::: "memory");
    __builtin_amdgcn_s_barrier();
    mfmaQ(0, 1);
    __builtin_amdgcn_s_barrier();
    // ---- ph2: reads (A mi4-7); stage B01(t+2) (q0,q1 consumed by end ph1) ---
    ldAhalf(D, 1);
    asm volatile("" ::: "memory");
    if (STG == 2) {
      gload_lds16(pB0, Bs + (D * 4 + 0) * 4096 + t * 8);
      gload_lds16(pB1, Bs + (D * 4 + 1) * 4096 + t * 8);
    }
    __builtin_amdgcn_s_barrier();
    mfmaQ(1, 0);
    __builtin_amdgcn_s_barrier();
    // ---- ph3: publish tile t+1; stage B23(t+2), A-even(t+2); MFMA wait-free -
    if (STG == 2)      asm volatile("s_waitcnt vmcnt(2)" ::: "memory");
    else if (STG == 1) asm volatile("s_waitcnt vmcnt(0)" ::: "memory");
    __builtin_amdgcn_sched_barrier(0);
    __builtin_amdgcn_s_barrier();
    if (STG == 2) {
      gload_lds16(pB2, Bs + (D * 4 + 2) * 4096 + t * 8);
      gload_lds16(pB3, Bs + (D * 4 + 3) * 4096 + t * 8);
      gload_lds16(pA0, As + (D * 4 + 0) * 4096 + t * 8);
      gload_lds16(pA2, As + (D * 4 + 2) * 4096 + t * 8);
    }
    __builtin_amdgcn_sched_barrier(0);
    mfmaQ(1, 1);
    __builtin_amdgcn_s_barrier();
    if (STG == 2) {
      pA0 += 64; pA1 += 64; pA2 += 64; pA3 += 64;
      pB0 += 64; pB1 += 64; pB2 += 64; pB3 += 64;
    }
  };

#pragma unroll 1
  for (int it = 0; it < NT / 2 - 1; ++it) {
    tile(ic<0>{}, ic<2>{});
    tile(ic<1>{}, ic<2>{});
  }
  tile(ic<0>{}, ic<1>{});
  tile(ic<1>{}, ic<0>{});

  // ---- epilogue: silu(gate)*up, gate/up 16-col interleave ----
  const int crow0 = bm0 + wm * 128;
#pragma unroll
  for (int mi = 0; mi < 8; ++mi) {
#pragma unroll
    for (int p = 0; p < 2; ++p) {
      const int ni = p * 2;
      const int col = ((bn0 + wn * 64 + ni * 16) >> 5) * 16 + lm;
#pragma unroll
      for (int r = 0; r < 4; ++r) {
        const int row = crow0 + mi * 16 + kb * 4 + r;
        const float gv = acc[mi][ni][r], uv = acc[mi][ni + 1][r];
        const float av = uv * (gv / (1.0f + __expf(-gv)));
        act[(size_t)row * 8192 + col] = (__bf16)av;
      }
    }
  }
}

// ---------- 128x128 GEMM, 64 KB LDS, 2 WGs/CU, quadrant-phased ---------------
// r13 RACE FIX: Bq0(t+2) stage moved ph1 -> ph2. At ph1 waves wn=0,1 read
// Bs[D*2+0] rows 16-31/48-63 (ni1) — the old same-phase overwrite of that
// quarter could land before the ds_read executed. Now: reads ph0 (A mi0-1 +
// B ni0), ph1 (B ni1), ph2 (A mi2-3); stages ph0: Aq1(t+1); ph2: Bq0(t+2),
// Bq1(t+2), Aq0(t+2) — each overwrite >=1 barrier after its readers' MFMA.
// Queue at ph3: [t-1.ph2 x3][t.ph0 x1][t.ph2 x3] = 7 -> steady vmcnt(3)
// drains exactly through tile t+1's last load. Prologue 7 loads, vmcnt(3).
template <int EPI, int KC>
__global__ __launch_bounds__(512, 4) void gemm128_kernel(
    const __bf16* __restrict__ A, const __bf16* __restrict__ Bt,
    void* __restrict__ Cv, const float* __restrict__ addend,
    int M, int N) {
  constexpr int NT = KC / 64;

  __shared__ alignas(16) __bf16 As[4 * 4096];
  __shared__ alignas(16) __bf16 Bs[4 * 4096];

  const int t = threadIdx.x;
  const int w = t >> 6, l = t & 63;
  const int lm = l & 15, kb = l >> 4;
  const int l7 = lm & 7;
  const int wm = w >> 2, wn = w & 3;

  const size_t stat = (size_t)(t >> 3) * KC + (size_t)(((t & 7) ^ ((t >> 3) & 7)) << 3);

  const int nwg = gridDim.x;
  const int bid = blockIdx.x;
  const int swz = (bid & 7) * (nwg >> 3) + (bid >> 3);
  const int nbm = M >> 7;
  const int per_g = nbm * 8;
  const int grp = swz / per_g, v = swz % per_g;
  const int bm0 = (v % nbm) * 128;
  const int bn0 = (grp * 8 + v / nbm) * 128;

  const __bf16* Ab = A + (size_t)bm0 * KC;
  const __bf16* Bb = Bt + (size_t)bn0 * KC;

  const uint32_t gsw0 = (uint32_t)((kb ^ l7) << 4);
  const uint32_t gsw1 = (uint32_t)(((4 + kb) ^ l7) << 4);
  const uint32_t aoff0 = (uint32_t)((wm * 32 + lm) * 128) + gsw0;
  const uint32_t aoff1 = (uint32_t)((wm * 32 + lm) * 128) + gsw1;
  const uint32_t bbase = (uint32_t)(((wn & 1) * 32 + lm) * 128 + (wn >> 1) * 8192);
  const uint32_t boff0 = bbase + gsw0, boff1 = bbase + gsw1;
  const char* AsC = (const char*)As;
  const char* BsC = (const char*)Bs;

  f32x4 acc[4][2] = {};
  bf16x8 af2[2][2];
  bf16x8 bfrq[2][2];

  auto ldApair = [&](int dD, int half) {
#pragma unroll
    for (int m2 = 0; m2 < 2; ++m2) {
      const int mi = half * 2 + m2;
      const uint32_t imA = (uint32_t)((dD * 2 + (mi >> 1)) * 8192 + (mi & 1) * 2048);
      af2[m2][0] = *(const bf16x8*)(AsC + aoff0 + imA);
      af2[m2][1] = *(const bf16x8*)(AsC + aoff1 + imA);
    }
  };
  auto ldBq = [&](int dD, int ni) {
    const uint32_t imB = (uint32_t)(dD * 16384 + ni * 2048);
    bfrq[ni][0] = *(const bf16x8*)(BsC + boff0 + imB);
    bfrq[ni][1] = *(const bf16x8*)(BsC + boff1 + imB);
  };
  auto mfmaQ = [&](int qm, int ni) {
    __builtin_amdgcn_s_setprio(1);
#pragma unroll
    for (int kk = 0; kk < 2; ++kk)
#pragma unroll
      for (int m2 = 0; m2 < 2; ++m2)
        acc[qm * 2 + m2][ni] = __builtin_amdgcn_mfma_f32_16x16x32_bf16(
            af2[m2][kk], bfrq[ni][kk], acc[qm * 2 + m2][ni], 0, 0, 0);
    __builtin_amdgcn_s_setprio(0);
  };

  // ---- prologue: A(0)q0,q1; B(0)q0,q1; B(1)q0,q1; A(1)q0; vmcnt(3) ----
  gload_lds16(Ab + stat,                        As + 0 * 4096 + t * 8);
  gload_lds16(Ab + stat + (size_t)64 * KC,      As + 1 * 4096 + t * 8);
  gload_lds16(Bb + stat,                        Bs + 0 * 4096 + t * 8);
  gload_lds16(Bb + stat + (size_t)64 * KC,      Bs + 1 * 4096 + t * 8);
  gload_lds16(Bb + stat + 64,                   Bs + 2 * 4096 + t * 8);
  gload_lds16(Bb + stat + (size_t)64 * KC + 64, Bs + 3 * 4096 + t * 8);
  gload_lds16(Ab + stat + 64,                   As + 2 * 4096 + t * 8);
  asm volatile("s_waitcnt vmcnt(3)" ::: "memory");
  __builtin_amdgcn_s_barrier();

  const __bf16* pAq1 = Ab + stat + (size_t)64 * KC + 64;   // A(t+1) q1
  const __bf16* pAq0 = Ab + stat + 128;                    // A(t+2) q0
  const __bf16* pBq0 = Bb + stat + 128;                    // B(t+2) q0
  const __bf16* pBq1 = Bb + stat + (size_t)64 * KC + 128;  // B(t+2) q1

  auto tile = [&](auto Dc, auto Sc) {
    constexpr int D = decltype(Dc)::value;
    constexpr int STG = decltype(Sc)::value;
    // ph0: reads A mi0-1 + B ni0; stage Aq1(t+1) -> other dbuf
    ldApair(D, 0);
    ldBq(D, 0);
    asm volatile("" ::: "memory");
    if (STG >= 1)
      gload_lds16(pAq1, As + ((D ^ 1) * 2 + 1) * 4096 + t * 8);
    __builtin_amdgcn_s_barrier();
    mfmaQ(0, 0);
    __builtin_amdgcn_s_barrier();
    // ph1: reads B ni1 (no stages — r13 race fix)
    ldBq(D, 1);
    asm volatile("" ::: "memory");
    __builtin_amdgcn_s_barrier();
    mfmaQ(0, 1);
    __builtin_amdgcn_s_barrier();
    // ph2: reads A mi2-3; stage Bq0(t+2), Bq1(t+2), Aq0(t+2)
    //      (B q0/q1 readers consumed by end ph1; A q0 readers by end ph0)
    ldApair(D, 1);
    asm volatile("" ::: "memory");
    if (STG == 2) {
      gload_lds16(pBq0, Bs + (D * 2 + 0) * 4096 + t * 8);
      gload_lds16(pBq1, Bs + (D * 2 + 1) * 4096 + t * 8);
      gload_lds16(pAq0, As + (D * 2 + 0) * 4096 + t * 8);
    }
    __builtin_amdgcn_s_barrier();
    mfmaQ(1, 0);
    __builtin_amdgcn_s_barrier();
    // ph3: publish tile t+1; no reads; MFMA wait-free
    if (STG == 2)      asm volatile("s_waitcnt vmcnt(3)" ::: "memory");
    else if (STG == 1) asm volatile("s_waitcnt vmcnt(0)" ::: "memory");
    __builtin_amdgcn_sched_barrier(0);
    __builtin_amdgcn_s_barrier();
    mfmaQ(1, 1);
    __builtin_amdgcn_s_barrier();
    if (STG == 2) { pAq0 += 64; pAq1 += 64; pBq0 += 64; pBq1 += 64; }
  };

#pragma unroll 1
  for (int it = 0; it < NT / 2 - 1; ++it) {
    tile(ic<0>{}, ic<2>{});
    tile(ic<1>{}, ic<2>{});
  }
  tile(ic<0>{}, ic<1>{});
  tile(ic<1>{}, ic<0>{});

  // ---- epilogue ----
#pragma unroll
  for (int mi = 0; mi < 4; ++mi) {
#pragma unroll
    for (int ni = 0; ni < 2; ++ni) {
      const int col = bn0 + wn * 32 + ni * 16 + lm;
#pragma unroll
      for (int r = 0; r < 4; ++r) {
        const int row = bm0 + (mi >> 1) * 64 + wm * 32 + (mi & 1) * 16 + kb * 4 + r;
        const size_t idx = (size_t)row * N + col;
        if (EPI == 0) ((__bf16*)Cv)[idx] = (__bf16)acc[mi][ni][r];
        else          ((float*)Cv)[idx] = addend[idx] + acc[mi][ni][r];
      }
    }
  }
}

extern "C" void kernel_launch(void* const* d_in, const int* in_sizes, int n_in,
                              void* d_out, int out_size, void* d_ws, size_t ws_size,
                              hipStream_t stream) {
  const float* x      = (const float*)d_in[0];
  const float* ln1    = (const float*)d_in[1];
  const float* ln2    = (const float*)d_in[2];
  const int*   qkv_qw = (const int*)d_in[3];
  const int*   qkv_qz = (const int*)d_in[4];
  const float* qkv_sc = (const float*)d_in[5];
  const int*   o_qw   = (const int*)d_in[6];
  const int*   o_qz   = (const int*)d_in[7];
  const float* o_sc   = (const float*)d_in[8];
  const int*   gu_qw  = (const int*)d_in[9];
  const int*   gu_qz  = (const int*)d_in[10];
  const float* gu_sc  = (const float*)d_in[11];
  const int*   dn_qw  = (const int*)d_in[12];
  const int*   dn_qz  = (const int*)d_in[13];
  const float* dn_sc  = (const float*)d_in[14];

  constexpr int M = 4096;

  char* ws = (char*)d_ws;
  __bf16* h   = (__bf16*)(ws + 0);                 // 16 MiB
  __bf16* q   = (__bf16*)(ws + 16777216ULL);       // 16 MiB
  float*  x2  = (float*)(ws + 33554432ULL);        // 32 MiB
  __bf16* W   = (__bf16*)(ws + 67108864ULL);       // 64 MiB weight^T (reused)
  __bf16* act = (__bf16*)(ws + 134217728ULL);      // 64 MiB [4096][8192]
  __bf16* Wdn = (__bf16*)(ws + 0);                 // 32 MiB (h,q dead by then)

  // 1. h1 = rmsnorm(x, ln1)
  rmsnorm_kernel<<<dim3(M), dim3(256), 0, stream>>>(x, ln1, h);
  // 2. Wq^T (only first 2048 cols of qkv used)
  dequant_t_kernel<0><<<dim3(16, 4), dim3(256), 0, stream>>>(qkv_qw, qkv_qz, qkv_sc, W, 2048, 768, 6144);
  // 3. q = h1 @ Wq
  gemm128_kernel<0, 2048><<<dim3(512), dim3(512), 0, stream>>>(h, W, (void*)q, nullptr, M, 2048);
  // 4. Wo^T
  dequant_t_kernel<0><<<dim3(16, 4), dim3(256), 0, stream>>>(o_qw, o_qz, o_sc, W, 2048, 256, 2048);
  // 5. x2 = x + q @ Wo
  gemm128_kernel<1, 2048><<<dim3(512), dim3(512), 0, stream>>>(q, W, (void*)x2, x, M, 2048);
  // 6. h2 = rmsnorm(x2, ln2)
  rmsnorm_kernel<<<dim3(M), dim3(256), 0, stream>>>(x2, ln2, h);
  // 7. Wgu^T [16384][2048], gate/up 16-col interleaved
  dequant_t_kernel<1><<<dim3(16, 32), dim3(256), 0, stream>>>(gu_qw, gu_qz, gu_sc, W, 2048, 2048, 16384);
  // 8. act = silu(gate)*up fused into GEMM epilogue
  gemm256_kernel<2048><<<dim3(1024), dim3(512), 0, stream>>>(h, W, act, M);
  // 9. Wdn^T [2048][8192]
  dequant_t_kernel<0><<<dim3(64, 4), dim3(256), 0, stream>>>(dn_qw, dn_qz, dn_sc, Wdn, 8192, 256, 2048);
  // 10. out = x2 + act @ Wdn
  gemm128_kernel<1, 8192><<<dim3(512), dim3(512), 0, stream>>>(act, Wdn, d_out, x2, M, 2048);
}